// Round 3
// baseline (175.617 us; speedup 1.0000x reference)
//
#include <hip/hip_runtime.h>
#include <hip/hip_bf16.h>
#include <math.h>

// Problem constants
#define BATCH 8192
#define HD    256
#define NPTS  51              // nb_steps=50 -> 51 quadrature points
#define MTOT  (BATCH*NPTS)    // 417792 = 256 * 1632
#define NTILES 1632           // 256-row m-tiles

typedef __bf16 bf16x8 __attribute__((ext_vector_type(8)));
typedef float  f32x4  __attribute__((ext_vector_type(4)));

// ---- workspace layout (bytes) ----
#define OFF_IW2P  0            // 65536 ushort: iw2 bf16, CHUNK-MAJOR per col-half:
                               //   iw2p[h*32768 + c*1024 + n*8 + j] = bf16(iw2[(h*128+n)*256 + c*8 + j])
#define OFF_W1X   131072       // 256 f32 (iw1[:,0])
#define OFF_CC    132096       // 64 f32
#define OFF_STEPS 132352       // 64 f32
#define OFF_OFFS  132608       // 8192 f32
#define OFF_SCAL  165376       // 8192 f32
#define OFF_G1    198144       // 8192*256 f32 (h-part of layer1 + ib1, NO relu)
#define OFF_FV0   8586752      // 417792 f32 partial dot, col-half 0
#define OFF_FV1   10257920     // 417792 f32 partial dot, col-half 1

__device__ __forceinline__ unsigned short f2bf(float f) {
    union { float f; unsigned u; } v; v.f = f;
    unsigned r = v.u + 0x7FFFu + ((v.u >> 16) & 1u);   // RTNE
    return (unsigned short)(r >> 16);
}

__device__ __forceinline__ unsigned pk2bf(float lo, float hi) {
    __hip_bfloat162 t = __float22bfloat162_rn(float2{lo, hi});
    union { __hip_bfloat162 b; unsigned u; } v; v.b = t;
    return v.u;
}

// ---------------- K1: fused prep + second network (unchanged) ----------------
__global__ void k1_fused(const float* __restrict__ iw2, const float* __restrict__ nw1,
                         const float* __restrict__ iw1, const float* __restrict__ ib1,
                         const float* __restrict__ nb1, const float* __restrict__ h,
                         const float* __restrict__ nw2, const float* __restrict__ nb2,
                         const float* __restrict__ nw3, const float* __restrict__ nb3,
                         unsigned short* iw2p, float* w1xs, float* cc, float* steps,
                         float* __restrict__ g1, float* __restrict__ offs,
                         float* __restrict__ scal) {
    int blk = blockIdx.x, tid = threadIdx.x;
    if (blk < 256) {
        int t = blk * 256 + tid;           // t = n*256 + k
        int n = t >> 8, k = t & 255;
        int half = n >> 7, nl = n & 127, c = k >> 3, j = k & 7;
        iw2p[half * 32768 + c * 1024 + nl * 8 + j] = f2bf(iw2[t]);
    } else if (blk == 256) {
        w1xs[tid] = iw1[tid * 16];   // column 0 of iw1
        const float PI_F = 3.14159265358979323846f;
        if (tid <= 50) {
            int j = tid;
            float s = 0.f;
            for (int i = 0; i <= 50; i += 2) {          // odd i have W=0
                float w = (i == 0) ? 1.f : 2.f / (1.f - (float)(i * i));
                float l;
                if (j == 0 || j == 50) l = 0.5f;
                else { int r = (i * j) % 100; l = __cosf((float)r * (PI_F / 50.f)); }
                s += l * w;
            }
            cc[j]    = s * (2.f / 50.f);
            steps[j] = __cosf((float)j * (PI_F / 50.f));
        }
    } else {
        __shared__ float hs[16][15];
        __shared__ unsigned short a1s[16][264];   // bf16 relu(h@nw1.T+nb1), padded stride
        __shared__ float Pp[4 * 2 * 16];
        int b0 = (blk - 257) * 16, n = tid;
        if (tid < 240) { int bb = tid / 15, j = tid % 15; hs[bb][j] = h[(b0 + bb) * 15 + j]; }
        __syncthreads();
        float ir[16], nr[15];
        const float4* ip = (const float4*)(iw1 + n * 16);
        ((float4*)ir)[0] = ip[0]; ((float4*)ir)[1] = ip[1];
        ((float4*)ir)[2] = ip[2]; ((float4*)ir)[3] = ip[3];
        #pragma unroll
        for (int j = 0; j < 15; ++j) nr[j] = nw1[n * 15 + j];
        float bi = ib1[n], bn = nb1[n];
        #pragma unroll
        for (int bb = 0; bb < 16; ++bb) {
            float g = bi, a = bn;
            #pragma unroll
            for (int j = 0; j < 15; ++j) { float hv = hs[bb][j]; g += hv * ir[j + 1]; a += hv * nr[j]; }
            g1[(b0 + bb) * 256 + n] = g;
            a1s[bb][n] = f2bf(fmaxf(a, 0.f));
        }
        __syncthreads();

        // ---- nnet layer2 MFMA: A = a1s (16 batches x 256k), wave w owns 64 n ----
        int lane = tid & 63, w = tid >> 6, l16 = lane & 15, quad = lane >> 4;
        f32x4 acc[4];
        #pragma unroll
        for (int nt = 0; nt < 4; ++nt) acc[nt] = (f32x4){0.f, 0.f, 0.f, 0.f};
        #pragma unroll
        for (int ks = 0; ks < 8; ++ks) {
            bf16x8 af = *(const bf16x8*)&a1s[l16][ks * 32 + quad * 8];
            #pragma unroll
            for (int nt = 0; nt < 4; ++nt) {
                const float* np = nw2 + (w * 64 + nt * 16 + l16) * 256 + ks * 32 + quad * 8;
                float4 f0 = ((const float4*)np)[0];
                float4 f1 = ((const float4*)np)[1];
                union { uint4 u; bf16x8 v; } bf;
                bf.u.x = pk2bf(f0.x, f0.y); bf.u.y = pk2bf(f0.z, f0.w);
                bf.u.z = pk2bf(f1.x, f1.y); bf.u.w = pk2bf(f1.z, f1.w);
                acc[nt] = __builtin_amdgcn_mfma_f32_16x16x32_bf16(af, bf.v, acc[nt], 0, 0, 0);
            }
        }
        float p0[4], p1[4];
        #pragma unroll
        for (int i = 0; i < 4; ++i) { p0[i] = 0.f; p1[i] = 0.f; }
        #pragma unroll
        for (int nt = 0; nt < 4; ++nt) {
            int nn = w * 64 + nt * 16 + l16;
            float bias = nb2[nn], wa = nw3[nn], wb = nw3[256 + nn];
            #pragma unroll
            for (int i = 0; i < 4; ++i) {
                float v = acc[nt][i] + bias;
                v = v > 0.f ? v : 0.f;
                p0[i] += v * wa;
                p1[i] += v * wb;
            }
        }
        #pragma unroll
        for (int mask = 1; mask < 16; mask <<= 1)
            #pragma unroll
            for (int i = 0; i < 4; ++i) {
                p0[i] += __shfl_xor(p0[i], mask, 64);
                p1[i] += __shfl_xor(p1[i], mask, 64);
            }
        if (l16 == 0) {
            #pragma unroll
            for (int i = 0; i < 4; ++i) {
                int r = quad * 4 + i;                  // 0..15
                Pp[w * 32 + r]      = p0[i];
                Pp[w * 32 + 16 + r] = p1[i];
            }
        }
        __syncthreads();
        if (tid < 16) {
            float s0 = Pp[tid]      + Pp[32 + tid] + Pp[64 + tid] + Pp[96 + tid]  + nb3[0];
            float s1 = Pp[16 + tid] + Pp[48 + tid] + Pp[80 + tid] + Pp[112 + tid] + nb3[1];
            offs[b0 + tid] = s0;
            scal[b0 + tid] = __expf(s1);
        }
    }
}

// ---------------- k2: persistent full-B-resident GEMM ----------------
// R12: R2's persistent structure spilled (WRITE_SIZE 16.5MB): full 8-k-step
// unroll + 128 AGPR acc blew the 256-reg budget. Fixes:
//  (a) #pragma unroll 2 on ks loop -> R1-like live ranges (108 arch regs fit).
//  (b) wave aspect mt=4,nt=8 (64 rows x 128 cols): LDS reads per 32-MFMA
//      k-step drop 22 -> 18 (B 8 + A 4x2 + w1x 2). k2 is LDS-read-pipe-bound,
//      so -18% traffic. 8 waves = 256 rows x 2 col-halves; acc[4][8]=128 AGPR.
// Per tile: one 8KB g1 DMA (dbuf) + ONE barrier; no barriers in k-body.
// Col-half partial sums -> fv0/fv1; k4 adds them.
__launch_bounds__(512, 2)
__global__ void k2_main(const float* __restrict__ x, const float* __restrict__ g1,
                        const float* __restrict__ w1xs, const unsigned short* __restrict__ iw2p,
                        const float* __restrict__ ib2, const float* __restrict__ iw3,
                        const float* __restrict__ steps,
                        float* __restrict__ fv0, float* __restrict__ fv1) {
    __shared__ __align__(16) unsigned char smem[148480];  // [0,128K) B | [128K,+16K) g1 dbuf | [+1K) w1x

    int tid = threadIdx.x;
    int lane = tid & 63, w = tid >> 6;
    int rg = w >> 1;                          // row-group 0..3 (64 rows each)
    int ch = w & 1;                           // col-half 0/1
    int l16 = lane & 15, quad = lane >> 4;

    // ---- stage full B (128 KB), w1x (1 KB), g1 for first tile (8 KB) ----
    #pragma unroll
    for (int it = 0; it < 16; ++it)
        __builtin_amdgcn_global_load_lds(
            (const __attribute__((address_space(1))) unsigned int*)((const unsigned char*)iw2p + tid * 16 + it * 8192),
            (__attribute__((address_space(3))) unsigned int*)(smem + tid * 16 + it * 8192),
            16, 0, 0);
    if (tid < 64)
        __builtin_amdgcn_global_load_lds(
            (const __attribute__((address_space(1))) unsigned int*)((const unsigned char*)w1xs + tid * 16),
            (__attribute__((address_space(3))) unsigned int*)(smem + 147456 + tid * 16),
            16, 0, 0);
    {
        int m0 = blockIdx.x * 256;
        unsigned blo = (unsigned)(((unsigned long long)(unsigned)m0 * 657931ull) >> 25);  // m0/51
        __builtin_amdgcn_global_load_lds(
            (const __attribute__((address_space(1))) unsigned int*)((const unsigned char*)(g1 + blo * 256) + tid * 16),
            (__attribute__((address_space(3))) unsigned int*)(smem + 131072 + tid * 16),
            16, 0, 0);
    }
    __syncthreads();

    const float* Wl = (const float*)(smem + 147456);           // [256] w1x
    const unsigned char* Bbase = smem + ch * 65536;            // this wave's col-half
    float* fvh = ch ? fv1 : fv0;

    // loop-invariant epilogue constants (16 regs)
    float bias_[8], w3_[8];
    #pragma unroll
    for (int nt = 0; nt < 8; ++nt) {
        int n = ch * 128 + nt * 16 + l16;
        bias_[nt] = ib2[n];
        w3_[nt]   = iw3[n];
    }

    int p = 0;
    for (int t = blockIdx.x; t < NTILES; t += 256, p ^= 1) {
        int m0 = t * 256;
        unsigned blo = (unsigned)(((unsigned long long)(unsigned)m0 * 657931ull) >> 25);

        // prefetch next tile's g1 rows into other buffer (drained by tile-end barrier)
        if (t + 256 < NTILES) {
            int m0n = (t + 256) * 256;
            unsigned blon = (unsigned)(((unsigned long long)(unsigned)m0n * 657931ull) >> 25);
            __builtin_amdgcn_global_load_lds(
                (const __attribute__((address_space(1))) unsigned int*)((const unsigned char*)(g1 + blon * 256) + tid * 16),
                (__attribute__((address_space(3))) unsigned int*)(smem + 131072 + (p ^ 1) * 8192 + tid * 16),
                16, 0, 0);
        }

        // per-row constants: batch rel offset within staged 8 rows, x-scale
        float xs_[4]; int rel_[4];
        #pragma unroll
        for (int mt = 0; mt < 4; ++mt) {
            int m = m0 + rg * 64 + mt * 16 + l16;
            unsigned b = (unsigned)(((unsigned long long)(unsigned)m * 657931ull) >> 25);  // m/51
            int pp = m - (int)b * 51;
            xs_[mt] = x[b] * (steps[pp] + 1.f) * 0.5f;
            rel_[mt] = (int)(b - blo) * 256;
        }
        const float* Ag = (const float*)(smem + 131072 + p * 8192);   // [8][256] g1 rows

        f32x4 acc[4][8];
        #pragma unroll
        for (int mt = 0; mt < 4; ++mt)
            #pragma unroll
            for (int nt = 0; nt < 8; ++nt)
                acc[mt][nt] = (f32x4){0.f, 0.f, 0.f, 0.f};

        #pragma unroll 2
        for (int ks = 0; ks < 8; ++ks) {
            int ko = ks * 32 + quad * 8;

            // ---- A fragments once per k-step (af[4] = 16 VGPRs) ----
            union { uint4 u; bf16x8 v; } af[4];
            {
                float4 w0 = ((const float4*)(Wl + ko))[0];
                float4 w1 = ((const float4*)(Wl + ko))[1];
                #pragma unroll
                for (int mt = 0; mt < 4; ++mt) {
                    const float* gp = Ag + rel_[mt] + ko;
                    float4 ga  = ((const float4*)gp)[0];
                    float4 gb2 = ((const float4*)gp)[1];
                    float xs = xs_[mt];
                    float a0 = fmaxf(ga.x  + xs * w0.x, 0.f);
                    float a1 = fmaxf(ga.y  + xs * w0.y, 0.f);
                    float a2 = fmaxf(ga.z  + xs * w0.z, 0.f);
                    float a3 = fmaxf(ga.w  + xs * w0.w, 0.f);
                    float a4 = fmaxf(gb2.x + xs * w1.x, 0.f);
                    float a5 = fmaxf(gb2.y + xs * w1.y, 0.f);
                    float a6 = fmaxf(gb2.z + xs * w1.z, 0.f);
                    float a7 = fmaxf(gb2.w + xs * w1.w, 0.f);
                    af[mt].u.x = pk2bf(a0, a1); af[mt].u.y = pk2bf(a2, a3);
                    af[mt].u.z = pk2bf(a4, a5); af[mt].u.w = pk2bf(a6, a7);
                }
            }

            // B byte addr within col-half: (ks*4+quad)*2048 + idx*256 + l16*16
            int cb = (ks * 4 + quad) * 2048 + l16 * 16;
            #pragma unroll
            for (int g = 0; g < 2; ++g) {            // 2 groups of 4 col-tiles
                bf16x8 bfr[4];
                #pragma unroll
                for (int nt = 0; nt < 4; ++nt)
                    bfr[nt] = *(const bf16x8*)(Bbase + cb + (g * 4 + nt) * 256);
                #pragma unroll
                for (int mt = 0; mt < 4; ++mt)
                    #pragma unroll
                    for (int nt = 0; nt < 4; ++nt)
                        acc[mt][g * 4 + nt] = __builtin_amdgcn_mfma_f32_16x16x32_bf16(
                            af[mt].v, bfr[nt], acc[mt][g * 4 + nt], 0, 0, 0);
            }
        }

        // ---- epilogue: relu(+ib2), dot iw3 over this half's 128 cols ----
        float pf[4][4];
        #pragma unroll
        for (int mt = 0; mt < 4; ++mt)
            #pragma unroll
            for (int i = 0; i < 4; ++i) pf[mt][i] = 0.f;
        #pragma unroll
        for (int nt = 0; nt < 8; ++nt) {
            float bias = bias_[nt], w3 = w3_[nt];
            #pragma unroll
            for (int mt = 0; mt < 4; ++mt)
                #pragma unroll
                for (int i = 0; i < 4; ++i) {
                    float v = acc[mt][nt][i] + bias;
                    v = v > 0.f ? v : 0.f;
                    pf[mt][i] += v * w3;
                }
        }
        #pragma unroll
        for (int mask = 1; mask < 16; mask <<= 1)
            #pragma unroll
            for (int mt = 0; mt < 4; ++mt)
                #pragma unroll
                for (int i = 0; i < 4; ++i)
                    pf[mt][i] += __shfl_xor(pf[mt][i], mask, 64);
        if (l16 == 0) {
            #pragma unroll
            for (int mt = 0; mt < 4; ++mt)
                #pragma unroll
                for (int i = 0; i < 4; ++i)
                    fvh[m0 + rg * 64 + mt * 16 + quad * 4 + i] = pf[mt][i];
        }

        __syncthreads();   // waves done with g1 buf p; next-tile DMA (buf p^1) drained
    }
}

// ---------------- k4: elu + quadrature reduce + combine (wave per batch) ----------------
__global__ void k4_final(const float* __restrict__ x, const float* __restrict__ fv0,
                         const float* __restrict__ fv1, const float* __restrict__ ib3,
                         const float* __restrict__ cc,
                         const float* __restrict__ offs, const float* __restrict__ scal,
                         float* __restrict__ out) {
    int tid = threadIdx.x;
    int wv = tid >> 6, lane = tid & 63;
    int b = blockIdx.x * 4 + wv;
    float v = 0.f;
    if (lane < 51) {
        int m = b * 51 + lane;
        float s = fv0[m] + fv1[m] + ib3[0];
        float f = s > 0.f ? s + 1.f : __expf(s);   // elu(s)+1
        v = f * cc[lane];
    }
    #pragma unroll
    for (int mask = 1; mask < 64; mask <<= 1) v += __shfl_xor(v, mask, 64);
    if (lane == 0)
        out[b] = scal[b] * (0.5f * x[b] * v) + offs[b];
}

extern "C" void kernel_launch(void* const* d_in, const int* in_sizes, int n_in,
                              void* d_out, int out_size, void* d_ws, size_t ws_size,
                              hipStream_t stream) {
    const float* x   = (const float*)d_in[0];
    const float* h   = (const float*)d_in[1];
    const float* iw1 = (const float*)d_in[2];
    const float* ib1 = (const float*)d_in[3];
    const float* iw2 = (const float*)d_in[4];
    const float* ib2 = (const float*)d_in[5];
    const float* iw3 = (const float*)d_in[6];
    const float* ib3 = (const float*)d_in[7];
    const float* nw1 = (const float*)d_in[8];
    const float* nb1 = (const float*)d_in[9];
    const float* nw2 = (const float*)d_in[10];
    const float* nb2 = (const float*)d_in[11];
    const float* nw3 = (const float*)d_in[12];
    const float* nb3 = (const float*)d_in[13];
    float* out = (float*)d_out;

    char* ws = (char*)d_ws;
    unsigned short* iw2p = (unsigned short*)(ws + OFF_IW2P);
    float* w1xs  = (float*)(ws + OFF_W1X);
    float* cc    = (float*)(ws + OFF_CC);
    float* steps = (float*)(ws + OFF_STEPS);
    float* offs  = (float*)(ws + OFF_OFFS);
    float* scal  = (float*)(ws + OFF_SCAL);
    float* g1    = (float*)(ws + OFF_G1);
    float* fv0   = (float*)(ws + OFF_FV0);
    float* fv1   = (float*)(ws + OFF_FV1);

    k1_fused<<<dim3(769), dim3(256), 0, stream>>>(iw2, nw1, iw1, ib1, nb1, h,
                                                  nw2, nb2, nw3, nb3,
                                                  iw2p, w1xs, cc, steps, g1, offs, scal);
    k2_main<<<dim3(256), dim3(512), 0, stream>>>(x, g1, w1xs, iw2p, ib2, iw3,
                                                 steps, fv0, fv1);
    k4_final<<<dim3(BATCH / 4), dim3(256), 0, stream>>>(x, fv0, fv1, ib3, cc, offs, scal, out);
}

// Round 4
// 165.104 us; speedup vs baseline: 1.0637x; 1.0637x over previous
//
#include <hip/hip_runtime.h>
#include <hip/hip_bf16.h>
#include <math.h>

// Problem constants
#define BATCH 8192
#define HD    256
#define NPTS  51              // nb_steps=50 -> 51 quadrature points
#define MTOT  (BATCH*NPTS)    // 417792 = 256 * 1632
#define NTILES 1632           // 256-row m-tiles

typedef __bf16 bf16x8 __attribute__((ext_vector_type(8)));
typedef float  f32x4  __attribute__((ext_vector_type(4)));

// ---- workspace layout (bytes) ----
#define OFF_IW2P  0            // 65536 ushort: iw2 bf16, CHUNK-MAJOR per col-half:
                               //   iw2p[h*32768 + c*1024 + n*8 + j] = bf16(iw2[(h*128+n)*256 + c*8 + j])
#define OFF_W1X   131072       // 256 f32 (iw1[:,0])
#define OFF_CC    132096       // 64 f32
#define OFF_STEPS 132352       // 64 f32
#define OFF_OFFS  132608       // 8192 f32
#define OFF_SCAL  165376       // 8192 f32
#define OFF_G1    198144       // 8192*256 f32 (h-part of layer1 + ib1, NO relu)
#define OFF_FV0   8586752      // 417792 f32 partial dot, col-half 0
#define OFF_FV1   10257920     // 417792 f32 partial dot, col-half 1

__device__ __forceinline__ unsigned short f2bf(float f) {
    union { float f; unsigned u; } v; v.f = f;
    unsigned r = v.u + 0x7FFFu + ((v.u >> 16) & 1u);   // RTNE
    return (unsigned short)(r >> 16);
}

__device__ __forceinline__ unsigned pk2bf(float lo, float hi) {
    __hip_bfloat162 t = __float22bfloat162_rn(float2{lo, hi});
    union { __hip_bfloat162 b; unsigned u; } v; v.b = t;
    return v.u;
}

// ---------------- K1: prep only (repack iw2, w1x/cc/steps, g1) ----------------
// R13: nnet (offs/scal) moved into k2's grid — it has no dependency on k1's
// outputs, and total-minus-k2 has been a constant ~90us across rounds.
__global__ void k1_prep(const float* __restrict__ iw2, const float* __restrict__ iw1,
                        const float* __restrict__ ib1, const float* __restrict__ h,
                        unsigned short* iw2p, float* w1xs, float* cc, float* steps,
                        float* __restrict__ g1) {
    int blk = blockIdx.x, tid = threadIdx.x;
    if (blk < 256) {
        int t = blk * 256 + tid;           // t = n*256 + k
        int n = t >> 8, k = t & 255;
        int half = n >> 7, nl = n & 127, c = k >> 3, j = k & 7;
        iw2p[half * 32768 + c * 1024 + nl * 8 + j] = f2bf(iw2[t]);
    } else if (blk == 256) {
        w1xs[tid] = iw1[tid * 16];   // column 0 of iw1
        const float PI_F = 3.14159265358979323846f;
        if (tid <= 50) {
            int j = tid;
            float s = 0.f;
            for (int i = 0; i <= 50; i += 2) {          // odd i have W=0
                float w = (i == 0) ? 1.f : 2.f / (1.f - (float)(i * i));
                float l;
                if (j == 0 || j == 50) l = 0.5f;
                else { int r = (i * j) % 100; l = __cosf((float)r * (PI_F / 50.f)); }
                s += l * w;
            }
            cc[j]    = s * (2.f / 50.f);
            steps[j] = __cosf((float)j * (PI_F / 50.f));
        }
    } else {
        __shared__ float hs[16][15];
        int b0 = (blk - 257) * 16, n = tid;
        if (tid < 240) { int bb = tid / 15, j = tid % 15; hs[bb][j] = h[(b0 + bb) * 15 + j]; }
        __syncthreads();
        float ir[16];
        const float4* ip = (const float4*)(iw1 + n * 16);
        ((float4*)ir)[0] = ip[0]; ((float4*)ir)[1] = ip[1];
        ((float4*)ir)[2] = ip[2]; ((float4*)ir)[3] = ip[3];
        float bi = ib1[n];
        #pragma unroll
        for (int bb = 0; bb < 16; ++bb) {
            float g = bi;
            #pragma unroll
            for (int j = 0; j < 15; ++j) g += hs[bb][j] * ir[j + 1];
            g1[(b0 + bb) * 256 + n] = g;
        }
    }
}

// ---------------- k2: nnet blocks + persistent half-B GEMM blocks ----------------
// R13 theory: MFMA pipe needs 26.4us/CU total; R1-R3 ran at ~33% of it because
// 128-AGPR acc capped occupancy at 2 waves/SIMD (LDS->VALU->MFMA chain starves
// the pipe when both waves build A). Fix = R0's proven wave shape (32 rows x
// 128 cols, acc[2][8]=64 AGPR, ~60 arch regs -> 124 unified <= 128) at 4
// waves/SIMD: block owns ONE col-half of B (64KB LDS), 2 blocks/CU, persistent
// over 256-row tiles (one barrier per tile; k-body barrier-free). 512 nnet
// blocks lead the grid (independent work, fills the k1 gap).
__launch_bounds__(512, 4)
__global__ void k2_main(const float* __restrict__ x, const float* __restrict__ g1,
                        const float* __restrict__ w1xs, const unsigned short* __restrict__ iw2p,
                        const float* __restrict__ ib2, const float* __restrict__ iw3,
                        const float* __restrict__ steps,
                        const float* __restrict__ h, const float* __restrict__ nw1,
                        const float* __restrict__ nb1, const float* __restrict__ nw2,
                        const float* __restrict__ nb2, const float* __restrict__ nw3,
                        const float* __restrict__ nb3,
                        float* __restrict__ offs, float* __restrict__ scal,
                        float* __restrict__ fv0, float* __restrict__ fv1) {
    __shared__ __align__(16) unsigned char smem[78848];  // GEMM: [0,64K) B-half | [64K,+12K) g1 dbuf | [+1K) w1x
    int tid = threadIdx.x, bid = blockIdx.x;
    int lane = tid & 63, w = tid >> 6;
    int l16 = lane & 15, quad = lane >> 4;

    if (bid < 512) {
        // ================= nnet: offs/scal for batches [bid*16, +16) =================
        float* hs = (float*)smem;                              // [16][15]
        unsigned short* a1s = (unsigned short*)(smem + 1024);  // [16][264]
        float* Pp = (float*)(smem + 10240);                    // [128]
        int b0 = bid * 16;
        if (tid < 240) { int bb = tid / 15, j = tid % 15; hs[bb * 15 + j] = h[(b0 + bb) * 15 + j]; }
        __syncthreads();
        if (tid < 256) {
            int n = tid;
            float nr[15];
            #pragma unroll
            for (int j = 0; j < 15; ++j) nr[j] = nw1[n * 15 + j];
            float bn = nb1[n];
            #pragma unroll
            for (int bb = 0; bb < 16; ++bb) {
                float a = bn;
                #pragma unroll
                for (int j = 0; j < 15; ++j) a += hs[bb * 15 + j] * nr[j];
                a1s[bb * 264 + n] = f2bf(fmaxf(a, 0.f));
            }
        }
        __syncthreads();
        if (tid < 256) {
            f32x4 acc[4];
            #pragma unroll
            for (int nt = 0; nt < 4; ++nt) acc[nt] = (f32x4){0.f, 0.f, 0.f, 0.f};
            #pragma unroll
            for (int ks = 0; ks < 8; ++ks) {
                bf16x8 af = *(const bf16x8*)&a1s[l16 * 264 + ks * 32 + quad * 8];
                #pragma unroll
                for (int nt = 0; nt < 4; ++nt) {
                    const float* np = nw2 + (w * 64 + nt * 16 + l16) * 256 + ks * 32 + quad * 8;
                    float4 f0 = ((const float4*)np)[0];
                    float4 f1 = ((const float4*)np)[1];
                    union { uint4 u; bf16x8 v; } bf;
                    bf.u.x = pk2bf(f0.x, f0.y); bf.u.y = pk2bf(f0.z, f0.w);
                    bf.u.z = pk2bf(f1.x, f1.y); bf.u.w = pk2bf(f1.z, f1.w);
                    acc[nt] = __builtin_amdgcn_mfma_f32_16x16x32_bf16(af, bf.v, acc[nt], 0, 0, 0);
                }
            }
            float p0[4], p1[4];
            #pragma unroll
            for (int i = 0; i < 4; ++i) { p0[i] = 0.f; p1[i] = 0.f; }
            #pragma unroll
            for (int nt = 0; nt < 4; ++nt) {
                int nn = w * 64 + nt * 16 + l16;
                float bias = nb2[nn], wa = nw3[nn], wb = nw3[256 + nn];
                #pragma unroll
                for (int i = 0; i < 4; ++i) {
                    float v = acc[nt][i] + bias;
                    v = v > 0.f ? v : 0.f;
                    p0[i] += v * wa;
                    p1[i] += v * wb;
                }
            }
            #pragma unroll
            for (int mask = 1; mask < 16; mask <<= 1)
                #pragma unroll
                for (int i = 0; i < 4; ++i) {
                    p0[i] += __shfl_xor(p0[i], mask, 64);
                    p1[i] += __shfl_xor(p1[i], mask, 64);
                }
            if (l16 == 0) {
                #pragma unroll
                for (int i = 0; i < 4; ++i) {
                    int r = quad * 4 + i;
                    Pp[w * 32 + r]      = p0[i];
                    Pp[w * 32 + 16 + r] = p1[i];
                }
            }
        }
        __syncthreads();
        if (tid < 16) {
            float s0 = Pp[tid]      + Pp[32 + tid] + Pp[64 + tid] + Pp[96 + tid]  + nb3[0];
            float s1 = Pp[16 + tid] + Pp[48 + tid] + Pp[80 + tid] + Pp[112 + tid] + nb3[1];
            offs[b0 + tid] = s0;
            scal[b0 + tid] = __expf(s1);
        }
        return;
    }

    // ================= GEMM: persistent, one col-half of B resident =================
    int gb = bid - 512;           // 0..511
    int ch = gb & 1;              // col-half
    int t0 = gb >> 1;             // first tile 0..255

    // ---- stage B-half (64 KB), w1x (1 KB), g1 for first tile (6 KB) ----
    #pragma unroll
    for (int it = 0; it < 8; ++it)
        __builtin_amdgcn_global_load_lds(
            (const __attribute__((address_space(1))) unsigned int*)((const unsigned char*)iw2p + ch * 65536 + tid * 16 + it * 8192),
            (__attribute__((address_space(3))) unsigned int*)(smem + tid * 16 + it * 8192),
            16, 0, 0);
    if (tid < 64)
        __builtin_amdgcn_global_load_lds(
            (const __attribute__((address_space(1))) unsigned int*)((const unsigned char*)w1xs + tid * 16),
            (__attribute__((address_space(3))) unsigned int*)(smem + 77824 + tid * 16),
            16, 0, 0);
    {
        int m0 = t0 * 256;
        unsigned blo = (unsigned)(((unsigned long long)(unsigned)m0 * 657931ull) >> 25);  // m0/51
        if (tid < 384)
            __builtin_amdgcn_global_load_lds(
                (const __attribute__((address_space(1))) unsigned int*)((const unsigned char*)(g1 + blo * 256) + tid * 16),
                (__attribute__((address_space(3))) unsigned int*)(smem + 65536 + tid * 16),
                16, 0, 0);
    }
    __syncthreads();

    const float* Wl = (const float*)(smem + 77824);   // [256] w1x
    float* fvh = ch ? fv1 : fv0;

    int p = 0;
    for (int t = t0; t < NTILES; t += 256, p ^= 1) {
        int m0 = t * 256;
        unsigned blo = (unsigned)(((unsigned long long)(unsigned)m0 * 657931ull) >> 25);

        // prefetch next tile's 6 g1 rows into other buffer (drained by tile-end barrier)
        if (t + 256 < NTILES) {
            int m0n = (t + 256) * 256;
            unsigned blon = (unsigned)(((unsigned long long)(unsigned)m0n * 657931ull) >> 25);
            if (tid < 384)
                __builtin_amdgcn_global_load_lds(
                    (const __attribute__((address_space(1))) unsigned int*)((const unsigned char*)(g1 + blon * 256) + tid * 16),
                    (__attribute__((address_space(3))) unsigned int*)(smem + 65536 + (p ^ 1) * 6144 + tid * 16),
                    16, 0, 0);
        }

        // per-row constants: batch rel offset within staged 6 rows, x-scale
        float xs_[2]; int rel_[2];
        #pragma unroll
        for (int mt = 0; mt < 2; ++mt) {
            int m = m0 + w * 32 + mt * 16 + l16;
            unsigned b = (unsigned)(((unsigned long long)(unsigned)m * 657931ull) >> 25);  // m/51
            int pp = m - (int)b * 51;
            xs_[mt] = x[b] * (steps[pp] + 1.f) * 0.5f;
            rel_[mt] = (int)(b - blo) * 256;
        }
        const float* Ag = (const float*)(smem + 65536 + p * 6144);   // [6][256] g1 rows

        f32x4 acc[2][8];
        #pragma unroll
        for (int mt = 0; mt < 2; ++mt)
            #pragma unroll
            for (int nt = 0; nt < 8; ++nt)
                acc[mt][nt] = (f32x4){0.f, 0.f, 0.f, 0.f};

        #pragma unroll 2
        for (int ks = 0; ks < 8; ++ks) {
            int ko = ks * 32 + quad * 8;

            // ---- A fragments once per k-step (af[2] = 8 VGPRs) ----
            union { uint4 u; bf16x8 v; } af[2];
            {
                float4 w0 = ((const float4*)(Wl + ko))[0];
                float4 w1 = ((const float4*)(Wl + ko))[1];
                #pragma unroll
                for (int mt = 0; mt < 2; ++mt) {
                    const float* gp = Ag + rel_[mt] + ko;
                    float4 ga  = ((const float4*)gp)[0];
                    float4 gb2 = ((const float4*)gp)[1];
                    float xs = xs_[mt];
                    float a0 = fmaxf(ga.x  + xs * w0.x, 0.f);
                    float a1 = fmaxf(ga.y  + xs * w0.y, 0.f);
                    float a2 = fmaxf(ga.z  + xs * w0.z, 0.f);
                    float a3 = fmaxf(ga.w  + xs * w0.w, 0.f);
                    float a4 = fmaxf(gb2.x + xs * w1.x, 0.f);
                    float a5 = fmaxf(gb2.y + xs * w1.y, 0.f);
                    float a6 = fmaxf(gb2.z + xs * w1.z, 0.f);
                    float a7 = fmaxf(gb2.w + xs * w1.w, 0.f);
                    af[mt].u.x = pk2bf(a0, a1); af[mt].u.y = pk2bf(a2, a3);
                    af[mt].u.z = pk2bf(a4, a5); af[mt].u.w = pk2bf(a6, a7);
                }
            }

            // B byte addr within col-half: (ks*4+quad)*2048 + nt*256 + l16*16
            int cb = (ks * 4 + quad) * 2048 + l16 * 16;
            #pragma unroll
            for (int g = 0; g < 2; ++g) {            // 2 groups of 4 col-tiles
                bf16x8 bfr[4];
                #pragma unroll
                for (int nt = 0; nt < 4; ++nt)
                    bfr[nt] = *(const bf16x8*)(smem + cb + (g * 4 + nt) * 256);
                #pragma unroll
                for (int mt = 0; mt < 2; ++mt)
                    #pragma unroll
                    for (int nt = 0; nt < 4; ++nt)
                        acc[mt][g * 4 + nt] = __builtin_amdgcn_mfma_f32_16x16x32_bf16(
                            af[mt].v, bfr[nt], acc[mt][g * 4 + nt], 0, 0, 0);
            }
        }

        // ---- epilogue: relu(+ib2), dot iw3 over this half's 128 cols ----
        float pf[2][4];
        #pragma unroll
        for (int mt = 0; mt < 2; ++mt)
            #pragma unroll
            for (int i = 0; i < 4; ++i) pf[mt][i] = 0.f;
        #pragma unroll
        for (int nt = 0; nt < 8; ++nt) {
            int n = ch * 128 + nt * 16 + l16;
            float bias = ib2[n], w3 = iw3[n];
            #pragma unroll
            for (int mt = 0; mt < 2; ++mt)
                #pragma unroll
                for (int i = 0; i < 4; ++i) {
                    float v = acc[mt][nt][i] + bias;
                    v = v > 0.f ? v : 0.f;
                    pf[mt][i] += v * w3;
                }
        }
        #pragma unroll
        for (int mask = 1; mask < 16; mask <<= 1)
            #pragma unroll
            for (int mt = 0; mt < 2; ++mt)
                #pragma unroll
                for (int i = 0; i < 4; ++i)
                    pf[mt][i] += __shfl_xor(pf[mt][i], mask, 64);
        if (l16 == 0) {
            #pragma unroll
            for (int mt = 0; mt < 2; ++mt)
                #pragma unroll
                for (int i = 0; i < 4; ++i)
                    fvh[m0 + w * 32 + mt * 16 + quad * 4 + i] = pf[mt][i];
        }

        __syncthreads();   // waves done with g1 buf p; next-tile DMA (buf p^1) drained
    }
}

// ---------------- k4: elu + quadrature reduce + combine (wave per batch) ----------------
__global__ void k4_final(const float* __restrict__ x, const float* __restrict__ fv0,
                         const float* __restrict__ fv1, const float* __restrict__ ib3,
                         const float* __restrict__ cc,
                         const float* __restrict__ offs, const float* __restrict__ scal,
                         float* __restrict__ out) {
    int tid = threadIdx.x;
    int wv = tid >> 6, lane = tid & 63;
    int b = blockIdx.x * 4 + wv;
    float v = 0.f;
    if (lane < 51) {
        int m = b * 51 + lane;
        float s = fv0[m] + fv1[m] + ib3[0];
        float f = s > 0.f ? s + 1.f : __expf(s);   // elu(s)+1
        v = f * cc[lane];
    }
    #pragma unroll
    for (int mask = 1; mask < 64; mask <<= 1) v += __shfl_xor(v, mask, 64);
    if (lane == 0)
        out[b] = scal[b] * (0.5f * x[b] * v) + offs[b];
}

extern "C" void kernel_launch(void* const* d_in, const int* in_sizes, int n_in,
                              void* d_out, int out_size, void* d_ws, size_t ws_size,
                              hipStream_t stream) {
    const float* x   = (const float*)d_in[0];
    const float* h   = (const float*)d_in[1];
    const float* iw1 = (const float*)d_in[2];
    const float* ib1 = (const float*)d_in[3];
    const float* iw2 = (const float*)d_in[4];
    const float* ib2 = (const float*)d_in[5];
    const float* iw3 = (const float*)d_in[6];
    const float* ib3 = (const float*)d_in[7];
    const float* nw1 = (const float*)d_in[8];
    const float* nb1 = (const float*)d_in[9];
    const float* nw2 = (const float*)d_in[10];
    const float* nb2 = (const float*)d_in[11];
    const float* nw3 = (const float*)d_in[12];
    const float* nb3 = (const float*)d_in[13];
    float* out = (float*)d_out;

    char* ws = (char*)d_ws;
    unsigned short* iw2p = (unsigned short*)(ws + OFF_IW2P);
    float* w1xs  = (float*)(ws + OFF_W1X);
    float* cc    = (float*)(ws + OFF_CC);
    float* steps = (float*)(ws + OFF_STEPS);
    float* offs  = (float*)(ws + OFF_OFFS);
    float* scal  = (float*)(ws + OFF_SCAL);
    float* g1    = (float*)(ws + OFF_G1);
    float* fv0   = (float*)(ws + OFF_FV0);
    float* fv1   = (float*)(ws + OFF_FV1);

    k1_prep<<<dim3(769), dim3(256), 0, stream>>>(iw2, iw1, ib1, h,
                                                 iw2p, w1xs, cc, steps, g1);
    k2_main<<<dim3(1024), dim3(512), 0, stream>>>(x, g1, w1xs, iw2p, ib2, iw3, steps,
                                                  h, nw1, nb1, nw2, nb2, nw3, nb3,
                                                  offs, scal, fv0, fv1);
    k4_final<<<dim3(BATCH / 4), dim3(256), 0, stream>>>(x, fv0, fv1, ib3, cc, offs, scal, out);
}

// Round 5
// 158.891 us; speedup vs baseline: 1.1053x; 1.0391x over previous
//
#include <hip/hip_runtime.h>
#include <hip/hip_bf16.h>
#include <math.h>

// Problem constants
#define BATCH 8192
#define HD    256
#define NPTS  51              // nb_steps=50 -> 51 quadrature points
#define MTOT  (BATCH*NPTS)    // 417792 = 128 * 3264

typedef __bf16 bf16x8 __attribute__((ext_vector_type(8)));
typedef float  f32x4  __attribute__((ext_vector_type(4)));

// ---- workspace layout (bytes) ----
#define OFF_IW2P  0            // 65536 ushort: iw2 bf16, CHUNK-MAJOR per col-half:
                               //   iw2p[h*32768 + c*1024 + n*8 + j] = bf16(iw2[(h*128+n)*256 + c*8 + j])
#define OFF_W1X   131072       // 256 f32 (iw1[:,0])
#define OFF_CC    132096       // 64 f32
#define OFF_STEPS 132352       // 64 f32
#define OFF_OFFS  132608       // 8192 f32
#define OFF_SCAL  165376       // 8192 f32
#define OFF_FV0   8586752      // 417792 f32 partial dot, col-half 0
#define OFF_FV1   10257920     // 417792 f32 partial dot, col-half 1

__device__ __forceinline__ unsigned short f2bf(float f) {
    union { float f; unsigned u; } v; v.f = f;
    unsigned r = v.u + 0x7FFFu + ((v.u >> 16) & 1u);   // RTNE
    return (unsigned short)(r >> 16);
}

__device__ __forceinline__ unsigned pk2bf(float lo, float hi) {
    __hip_bfloat162 t = __float22bfloat162_rn(float2{lo, hi});
    union { __hip_bfloat162 b; unsigned u; } v; v.b = t;
    return v.u;
}

// ---------------- K1: tiny prep (repack iw2 + constants) ----------------
// R14: g1 fused into k2 (computed per-block from iw1/ib1/h); nnet lives in
// k2's grid head. k1 is now 257 small blocks.
__global__ void k1_prep(const float* __restrict__ iw2, const float* __restrict__ iw1,
                        unsigned short* iw2p, float* w1xs, float* cc, float* steps) {
    int blk = blockIdx.x, tid = threadIdx.x;
    if (blk < 256) {
        int t = blk * 256 + tid;           // t = n*256 + k  (n == blk)
        int n = t >> 8, k = t & 255;
        int half = n >> 7, nl = n & 127, c = k >> 3, j = k & 7;
        iw2p[half * 32768 + c * 1024 + nl * 8 + j] = f2bf(iw2[t]);
    } else {
        w1xs[tid] = iw1[tid * 16];   // column 0 of iw1
        const float PI_F = 3.14159265358979323846f;
        if (tid <= 50) {
            int j = tid;
            float s = 0.f;
            for (int i = 0; i <= 50; i += 2) {          // odd i have W=0
                float w = (i == 0) ? 1.f : 2.f / (1.f - (float)(i * i));
                float l;
                if (j == 0 || j == 50) l = 0.5f;
                else { int r = (i * j) % 100; l = __cosf((float)r * (PI_F / 50.f)); }
                s += l * w;
            }
            cc[j]    = s * (2.f / 50.f);
            steps[j] = __cosf((float)j * (PI_F / 50.f));
        }
    }
}

// ---------------- k2: nnet head blocks + R0-style GEMM blocks ----------------
// R14: GEMM body reverted to the proven R0 shape (128 rows x 128 cols, 4
// waves, acc[2][8]=64 AGPR, ~60 arch VGPR, 4 blocks/CU, 2-barrier dbuf
// B-streaming; 66.4us measured). New: g1 rows computed IN-BLOCK (iw1 float4
// loads + wave-uniform h s_loads + 60 FMA -> 4 ds_write) instead of staged
// from a global g1 array — removes k1's 512-block pass, its 8MB write and
// R0's 13.5MB FETCH. nnet (offs/scal) = first 512 blocks of this grid.
__launch_bounds__(256, 4)
__global__ void k2_main(const float* __restrict__ x,
                        const float* __restrict__ w1xs, const unsigned short* __restrict__ iw2p,
                        const float* __restrict__ ib2, const float* __restrict__ iw3,
                        const float* __restrict__ steps,
                        const float* __restrict__ h, const float* __restrict__ iw1,
                        const float* __restrict__ ib1,
                        const float* __restrict__ nw1, const float* __restrict__ nb1,
                        const float* __restrict__ nw2, const float* __restrict__ nb2,
                        const float* __restrict__ nw3, const float* __restrict__ nb3,
                        float* __restrict__ offs, float* __restrict__ scal,
                        float* __restrict__ fv0, float* __restrict__ fv1) {
    __shared__ __align__(16) unsigned char smem[37888];   // GEMM: [0,32K) B dbuf | [32K,36K) Ag | [36K,37K) w1x
    int tid = threadIdx.x, bid = blockIdx.x;
    int lane = tid & 63, w = tid >> 6;
    int l16 = lane & 15, quad = lane >> 4;

    if (bid < 512) {
        // ================= nnet: offs/scal for batches [bid*16, +16) =================
        float* hs = (float*)smem;                              // [16][15]
        unsigned short* a1s = (unsigned short*)(smem + 1024);  // [16][264]
        float* Pp = (float*)(smem + 10240);                    // [128]
        int b0 = bid * 16;
        if (tid < 240) { int bb = tid / 15, j = tid % 15; hs[bb * 15 + j] = h[(b0 + bb) * 15 + j]; }
        __syncthreads();
        {
            int n = tid;
            float nr[15];
            #pragma unroll
            for (int j = 0; j < 15; ++j) nr[j] = nw1[n * 15 + j];
            float bn = nb1[n];
            #pragma unroll
            for (int bb = 0; bb < 16; ++bb) {
                float a = bn;
                #pragma unroll
                for (int j = 0; j < 15; ++j) a += hs[bb * 15 + j] * nr[j];
                a1s[bb * 264 + n] = f2bf(fmaxf(a, 0.f));
            }
        }
        __syncthreads();
        {
            f32x4 acc[4];
            #pragma unroll
            for (int nt = 0; nt < 4; ++nt) acc[nt] = (f32x4){0.f, 0.f, 0.f, 0.f};
            #pragma unroll
            for (int ks = 0; ks < 8; ++ks) {
                bf16x8 af = *(const bf16x8*)&a1s[l16 * 264 + ks * 32 + quad * 8];
                #pragma unroll
                for (int nt = 0; nt < 4; ++nt) {
                    const float* np = nw2 + (w * 64 + nt * 16 + l16) * 256 + ks * 32 + quad * 8;
                    float4 f0 = ((const float4*)np)[0];
                    float4 f1 = ((const float4*)np)[1];
                    union { uint4 u; bf16x8 v; } bf;
                    bf.u.x = pk2bf(f0.x, f0.y); bf.u.y = pk2bf(f0.z, f0.w);
                    bf.u.z = pk2bf(f1.x, f1.y); bf.u.w = pk2bf(f1.z, f1.w);
                    acc[nt] = __builtin_amdgcn_mfma_f32_16x16x32_bf16(af, bf.v, acc[nt], 0, 0, 0);
                }
            }
            float p0[4], p1[4];
            #pragma unroll
            for (int i = 0; i < 4; ++i) { p0[i] = 0.f; p1[i] = 0.f; }
            #pragma unroll
            for (int nt = 0; nt < 4; ++nt) {
                int nn = w * 64 + nt * 16 + l16;
                float bias = nb2[nn], wa = nw3[nn], wb = nw3[256 + nn];
                #pragma unroll
                for (int i = 0; i < 4; ++i) {
                    float v = acc[nt][i] + bias;
                    v = v > 0.f ? v : 0.f;
                    p0[i] += v * wa;
                    p1[i] += v * wb;
                }
            }
            #pragma unroll
            for (int mask = 1; mask < 16; mask <<= 1)
                #pragma unroll
                for (int i = 0; i < 4; ++i) {
                    p0[i] += __shfl_xor(p0[i], mask, 64);
                    p1[i] += __shfl_xor(p1[i], mask, 64);
                }
            if (l16 == 0) {
                #pragma unroll
                for (int i = 0; i < 4; ++i) {
                    int r = quad * 4 + i;
                    Pp[w * 32 + r]      = p0[i];
                    Pp[w * 32 + 16 + r] = p1[i];
                }
            }
        }
        __syncthreads();
        if (tid < 16) {
            float s0 = Pp[tid]      + Pp[32 + tid] + Pp[64 + tid] + Pp[96 + tid]  + nb3[0];
            float s1 = Pp[16 + tid] + Pp[48 + tid] + Pp[80 + tid] + Pp[112 + tid] + nb3[1];
            offs[b0 + tid] = s0;
            scal[b0 + tid] = __expf(s1);
        }
        return;
    }

    // ================= GEMM block (R0 body + in-block g1) =================
    int gb = bid - 512;
    int hf = gb & 1;
    int m0 = (gb >> 1) * 128;
    float* Pp = (float*)smem;     // epilogue alias: [128][20] f32

    unsigned blo = (unsigned)(((unsigned long long)(unsigned)m0 * 657931ull) >> 25);  // m0/51

    const unsigned char* bsrc = (const unsigned char*)iw2p + hf * 65536 + tid * 16;

    // DMA B chunk 0 into buf 0 (16KB) and w1x (1KB)
    #pragma unroll
    for (int it = 0; it < 4; ++it)
        __builtin_amdgcn_global_load_lds(
            (const __attribute__((address_space(1))) unsigned int*)(bsrc + it * 4096),
            (__attribute__((address_space(3))) unsigned int*)(smem + tid * 16 + it * 4096),
            16, 0, 0);
    if (w == 0)
        __builtin_amdgcn_global_load_lds(
            (const __attribute__((address_space(1))) unsigned int*)((const unsigned char*)w1xs + lane * 16),
            (__attribute__((address_space(3))) unsigned int*)(smem + 36864 + lane * 16),
            16, 0, 0);

    // ---- compute this block's 4 g1 rows into Ag (replaces global g1 stage) ----
    // g1[b][n] = ib1[n] + sum_j h[b][j] * iw1[n][j+1]; n = tid, b = blo..blo+3
    {
        float ir[16];
        const float4* ip = (const float4*)(iw1 + tid * 16);
        ((float4*)ir)[0] = ip[0]; ((float4*)ir)[1] = ip[1];
        ((float4*)ir)[2] = ip[2]; ((float4*)ir)[3] = ip[3];
        float bi = ib1[tid];
        float* Agw = (float*)(smem + 32768);
        #pragma unroll
        for (int bb = 0; bb < 4; ++bb) {
            int bidx = (int)blo + bb; if (bidx > BATCH - 1) bidx = BATCH - 1;
            float g = bi;
            #pragma unroll
            for (int j = 0; j < 15; ++j) g += h[bidx * 15 + j] * ir[j + 1];   // h: wave-uniform -> s_load
            Agw[bb * 256 + tid] = g;
        }
    }

    // per-m-group row constants (batch rel offset, x-scale) — overlaps with DMA
    float xs_[2]; int rel_[2];
    #pragma unroll
    for (int mt = 0; mt < 2; ++mt) {
        int m = m0 + w * 32 + mt * 16 + l16;
        unsigned b = (unsigned)(((unsigned long long)(unsigned)m * 657931ull) >> 25);  // m/51
        int p = m - (int)b * 51;
        xs_[mt] = x[b] * (steps[p] + 1.f) * 0.5f;
        rel_[mt] = (int)(b - blo) * 256;
    }

    f32x4 acc[2][8];
    #pragma unroll
    for (int mt = 0; mt < 2; ++mt)
        #pragma unroll
        for (int nt = 0; nt < 8; ++nt)
            acc[mt][nt] = (f32x4){0.f, 0.f, 0.f, 0.f};

    const float* Ag = (const float*)(smem + 32768);   // [4][256] g1 rows
    const float* Wl = (const float*)(smem + 36864);   // [256] w1x

    #pragma unroll
    for (int kc = 0; kc < 4; ++kc) {
        __syncthreads();                       // DMA(kc) + Ag writes drained; waves aligned
        if (kc < 3) {                          // prefetch next chunk into other buf
            const unsigned char* s2 = bsrc + (kc + 1) * 16384;
            unsigned char* d2 = smem + ((kc + 1) & 1) * 16384 + tid * 16;
            #pragma unroll
            for (int it = 0; it < 4; ++it)
                __builtin_amdgcn_global_load_lds(
                    (const __attribute__((address_space(1))) unsigned int*)(s2 + it * 4096),
                    (__attribute__((address_space(3))) unsigned int*)(d2 + it * 4096),
                    16, 0, 0);
        }
        const unsigned short* Bl = (const unsigned short*)(smem + (kc & 1) * 16384);
        #pragma unroll
        for (int s = 0; s < 2; ++s) {
            int ks = kc * 2 + s;               // global 32-wide k-step 0..7
            int ko = ks * 32 + quad * 8;
            int cl = s * 4 + quad;             // chunk-local c 0..7

            // ---- both A fragments first (af[2] = 8 VGPRs) ----
            union { uint4 u; bf16x8 v; } af[2];
            {
                float4 w0 = ((const float4*)(Wl + ko))[0];
                float4 w1 = ((const float4*)(Wl + ko))[1];
                #pragma unroll
                for (int mt = 0; mt < 2; ++mt) {
                    const float* gp = Ag + rel_[mt] + ko;
                    float4 ga  = ((const float4*)gp)[0];
                    float4 gb2 = ((const float4*)gp)[1];
                    float xs = xs_[mt];
                    float a0 = fmaxf(ga.x  + xs * w0.x, 0.f);
                    float a1 = fmaxf(ga.y  + xs * w0.y, 0.f);
                    float a2 = fmaxf(ga.z  + xs * w0.z, 0.f);
                    float a3 = fmaxf(ga.w  + xs * w0.w, 0.f);
                    float a4 = fmaxf(gb2.x + xs * w1.x, 0.f);
                    float a5 = fmaxf(gb2.y + xs * w1.y, 0.f);
                    float a6 = fmaxf(gb2.z + xs * w1.z, 0.f);
                    float a7 = fmaxf(gb2.w + xs * w1.w, 0.f);
                    af[mt].u.x = pk2bf(a0, a1); af[mt].u.y = pk2bf(a2, a3);
                    af[mt].u.z = pk2bf(a4, a5); af[mt].u.w = pk2bf(a6, a7);
                }
            }

            // ---- B frags in two groups of 4 (bfr = 16 VGPRs live) ----
            #pragma unroll
            for (int g = 0; g < 2; ++g) {
                bf16x8 bfr[4];
                #pragma unroll
                for (int nt = 0; nt < 4; ++nt)
                    bfr[nt] = *(const bf16x8*)(Bl + (cl * 128 + (g * 4 + nt) * 16 + l16) * 8);
                #pragma unroll
                for (int mt = 0; mt < 2; ++mt)
                    #pragma unroll
                    for (int nt = 0; nt < 4; ++nt)
                        acc[mt][g * 4 + nt] = __builtin_amdgcn_mfma_f32_16x16x32_bf16(
                            af[mt].v, bfr[nt], acc[mt][g * 4 + nt], 0, 0, 0);
            }
        }
    }

    // ---- epilogue: relu(+ib2), dot with iw3 over this block's 128 cols ----
    float pf[2][4];
    #pragma unroll
    for (int mt = 0; mt < 2; ++mt)
        #pragma unroll
        for (int i = 0; i < 4; ++i) pf[mt][i] = 0.f;
    #pragma unroll
    for (int nt = 0; nt < 8; ++nt) {
        int n = hf * 128 + nt * 16 + l16;
        float bias = ib2[n], w3 = iw3[n];
        #pragma unroll
        for (int mt = 0; mt < 2; ++mt)
            #pragma unroll
            for (int i = 0; i < 4; ++i) {
                float v = acc[mt][nt][i] + bias;
                v = v > 0.f ? v : 0.f;
                pf[mt][i] += v * w3;
            }
    }
    __syncthreads();     // all Bl/Ag reads done; smem becomes Pp
    #pragma unroll
    for (int mt = 0; mt < 2; ++mt)
        #pragma unroll
        for (int i = 0; i < 4; ++i) {
            int row = w * 32 + mt * 16 + quad * 4 + i;
            Pp[row * 20 + l16] = pf[mt][i];
        }
    __syncthreads();
    if (tid < 128) {
        const float4* pp = (const float4*)(Pp + tid * 20);
        float4 v0 = pp[0], v1 = pp[1], v2 = pp[2], v3 = pp[3];
        float s = v0.x + v0.y + v0.z + v0.w + v1.x + v1.y + v1.z + v1.w
                + v2.x + v2.y + v2.z + v2.w + v3.x + v3.y + v3.z + v3.w;
        (hf ? fv1 : fv0)[m0 + tid] = s;     // partial (over 128 cols), pre-elu
    }
}

// ---------------- k4: elu + quadrature reduce + combine (wave per batch) ----------------
__global__ void k4_final(const float* __restrict__ x, const float* __restrict__ fv0,
                         const float* __restrict__ fv1, const float* __restrict__ ib3,
                         const float* __restrict__ cc,
                         const float* __restrict__ offs, const float* __restrict__ scal,
                         float* __restrict__ out) {
    int tid = threadIdx.x;
    int wv = tid >> 6, lane = tid & 63;
    int b = blockIdx.x * 4 + wv;
    float v = 0.f;
    if (lane < 51) {
        int m = b * 51 + lane;
        float s = fv0[m] + fv1[m] + ib3[0];
        float f = s > 0.f ? s + 1.f : __expf(s);   // elu(s)+1
        v = f * cc[lane];
    }
    #pragma unroll
    for (int mask = 1; mask < 64; mask <<= 1) v += __shfl_xor(v, mask, 64);
    if (lane == 0)
        out[b] = scal[b] * (0.5f * x[b] * v) + offs[b];
}

extern "C" void kernel_launch(void* const* d_in, const int* in_sizes, int n_in,
                              void* d_out, int out_size, void* d_ws, size_t ws_size,
                              hipStream_t stream) {
    const float* x   = (const float*)d_in[0];
    const float* h   = (const float*)d_in[1];
    const float* iw1 = (const float*)d_in[2];
    const float* ib1 = (const float*)d_in[3];
    const float* iw2 = (const float*)d_in[4];
    const float* ib2 = (const float*)d_in[5];
    const float* iw3 = (const float*)d_in[6];
    const float* ib3 = (const float*)d_in[7];
    const float* nw1 = (const float*)d_in[8];
    const float* nb1 = (const float*)d_in[9];
    const float* nw2 = (const float*)d_in[10];
    const float* nb2 = (const float*)d_in[11];
    const float* nw3 = (const float*)d_in[12];
    const float* nb3 = (const float*)d_in[13];
    float* out = (float*)d_out;

    char* ws = (char*)d_ws;
    unsigned short* iw2p = (unsigned short*)(ws + OFF_IW2P);
    float* w1xs  = (float*)(ws + OFF_W1X);
    float* cc    = (float*)(ws + OFF_CC);
    float* steps = (float*)(ws + OFF_STEPS);
    float* offs  = (float*)(ws + OFF_OFFS);
    float* scal  = (float*)(ws + OFF_SCAL);
    float* fv0   = (float*)(ws + OFF_FV0);
    float* fv1   = (float*)(ws + OFF_FV1);

    k1_prep<<<dim3(257), dim3(256), 0, stream>>>(iw2, iw1, iw2p, w1xs, cc, steps);
    k2_main<<<dim3(512 + (MTOT / 128) * 2), dim3(256), 0, stream>>>(
        x, w1xs, iw2p, ib2, iw3, steps, h, iw1, ib1,
        nw1, nb1, nw2, nb2, nw3, nb3, offs, scal, fv0, fv1);
    k4_final<<<dim3(BATCH / 4), dim3(256), 0, stream>>>(x, fv0, fv1, ib3, cc, offs, scal, out);
}